// Round 1
// baseline (619.002 us; speedup 1.0000x reference)
//
#include <hip/hip_runtime.h>
#include <hip/hip_bf16.h>
#include <cstddef>

// ToxicityGAT: 2-layer GAT (4 heads then 1 head) + linear classifier.
// N=50000 nodes, E=800000 edges (+N self loops), IN=128, HID=64, HEADS=4.
// Plan: dense GEMMs (fp32 vector ALU) + device-built CSR (by dst) +
// one-wave-per-node online-softmax aggregation (no atomics in hot loop).

#define HEADS 4
#define HID 64
#define IN_DIM 128

// ---------------- generic 64x64 fp32 tiled GEMM: C[M,Ncol] = A[M,K] @ B[K,Ncol]
template <int BK>
__global__ __launch_bounds__(256) void gemm_kernel(const float* __restrict__ A,
                                                   const float* __restrict__ B,
                                                   float* __restrict__ C,
                                                   int M, int K, int Ncol) {
    __shared__ float As[64][BK + 1];   // +1 pad: inner reads 2-way bank alias (free)
    __shared__ float Bs[BK][65];
    const int tid = threadIdx.x;
    const int tx = tid & 15, ty = tid >> 4;
    const int row0 = blockIdx.y * 64, col0 = blockIdx.x * 64;
    float acc[4][4] = {};
    for (int k0 = 0; k0 < K; k0 += BK) {
        for (int i = tid * 4; i < 64 * BK; i += 1024) {
            int r = i / BK, k = i - r * BK;
            int row = row0 + r;
            float4 v = make_float4(0.f, 0.f, 0.f, 0.f);
            if (row < M) v = *(const float4*)(A + (size_t)row * K + k0 + k);
            As[r][k] = v.x; As[r][k + 1] = v.y; As[r][k + 2] = v.z; As[r][k + 3] = v.w;
        }
        for (int i = tid * 4; i < BK * 64; i += 1024) {
            int r = i >> 6, c = i & 63;
            float4 v = *(const float4*)(B + (size_t)(k0 + r) * Ncol + col0 + c);
            Bs[r][c] = v.x; Bs[r][c + 1] = v.y; Bs[r][c + 2] = v.z; Bs[r][c + 3] = v.w;
        }
        __syncthreads();
#pragma unroll
        for (int k = 0; k < BK; ++k) {
            float a0 = As[ty * 4 + 0][k], a1 = As[ty * 4 + 1][k];
            float a2 = As[ty * 4 + 2][k], a3 = As[ty * 4 + 3][k];
            float b0 = Bs[k][tx * 4 + 0], b1 = Bs[k][tx * 4 + 1];
            float b2 = Bs[k][tx * 4 + 2], b3 = Bs[k][tx * 4 + 3];
            acc[0][0] += a0 * b0; acc[0][1] += a0 * b1; acc[0][2] += a0 * b2; acc[0][3] += a0 * b3;
            acc[1][0] += a1 * b0; acc[1][1] += a1 * b1; acc[1][2] += a1 * b2; acc[1][3] += a1 * b3;
            acc[2][0] += a2 * b0; acc[2][1] += a2 * b1; acc[2][2] += a2 * b2; acc[2][3] += a2 * b3;
            acc[3][0] += a3 * b0; acc[3][1] += a3 * b1; acc[3][2] += a3 * b2; acc[3][3] += a3 * b3;
        }
        __syncthreads();
    }
#pragma unroll
    for (int i = 0; i < 4; ++i) {
        int row = row0 + ty * 4 + i;
        if (row < M)
            *(float4*)(C + (size_t)row * Ncol + col0 + tx * 4) =
                make_float4(acc[i][0], acc[i][1], acc[i][2], acc[i][3]);
    }
}

// ---------------- CSR build ----------------
__global__ void deg_init_kernel(int* __restrict__ deg, int N) {
    int n = blockIdx.x * 256 + threadIdx.x;
    if (n < N) deg[n] = 1;  // self loop
}

__global__ void deg_count_kernel(const int* __restrict__ dst, int* __restrict__ deg, int E) {
    int e = blockIdx.x * 256 + threadIdx.x;
    if (e < E) atomicAdd(&deg[dst[e]], 1);
}

__global__ __launch_bounds__(1024) void scan_kernel(const int* __restrict__ deg,
                                                    int* __restrict__ row_ptr, int n) {
    __shared__ int wsum[16];
    __shared__ int carry_s;
    const int tid = threadIdx.x, lane = tid & 63, w = tid >> 6;
    if (tid == 0) carry_s = 0;
    __syncthreads();
    for (int base = 0; base < n; base += 1024) {
        int i = base + tid;
        int v = (i < n) ? deg[i] : 0;
        int x = v;
#pragma unroll
        for (int off = 1; off < 64; off <<= 1) {
            int y = __shfl_up(x, off, 64);
            if (lane >= off) x += y;
        }
        if (lane == 63) wsum[w] = x;
        __syncthreads();
        if (tid < 16) {
            int t = wsum[tid];
#pragma unroll
            for (int off = 1; off < 16; off <<= 1) {
                int y = __shfl_up(t, off, 64);
                if (tid >= off) t += y;
            }
            wsum[tid] = t;
        }
        __syncthreads();
        int carry = carry_s;
        if (i < n) row_ptr[i] = carry + (w ? wsum[w - 1] : 0) + x - v;
        __syncthreads();
        if (tid == 0) carry_s = carry + wsum[15];
        __syncthreads();
    }
    if (threadIdx.x == 0) row_ptr[n] = carry_s;
}

__global__ void selfloop_kernel(const int* __restrict__ row_ptr, int* __restrict__ colA,
                                int* __restrict__ fill, int N) {
    int n = blockIdx.x * 256 + threadIdx.x;
    if (n < N) {
        int p = row_ptr[n];
        colA[p] = n;       // self loop first
        fill[n] = p + 1;
    }
}

__global__ void scatter_kernel(const int* __restrict__ src, const int* __restrict__ dst,
                               int* __restrict__ fill, int* __restrict__ colA, int E) {
    int e = blockIdx.x * 256 + threadIdx.x;
    if (e < E) {
        int pos = atomicAdd(&fill[dst[e]], 1);
        colA[pos] = src[e];
    }
}

// ---------------- attention score dots ----------------
// as1[n][h] = dot(g1[n,h,:], att_src[h,:]); ad1 likewise. One wave per node.
__global__ __launch_bounds__(256) void alpha1_kernel(const float* __restrict__ g1,
                                                     const float* __restrict__ att_src,
                                                     const float* __restrict__ att_dst,
                                                     float* __restrict__ as1,
                                                     float* __restrict__ ad1, int N) {
    int wid = (blockIdx.x * 256 + threadIdx.x) >> 6;
    int lane = threadIdx.x & 63;
    if (wid >= N) return;
    const float* g = g1 + (size_t)wid * (HEADS * HID);
    float sv[4], dv[4];
#pragma unroll
    for (int h = 0; h < HEADS; ++h) {
        float v = g[h * HID + lane];
        float s = v * att_src[h * HID + lane];
        float d = v * att_dst[h * HID + lane];
#pragma unroll
        for (int off = 32; off; off >>= 1) {
            s += __shfl_xor(s, off, 64);
            d += __shfl_xor(d, off, 64);
        }
        sv[h] = s; dv[h] = d;
    }
    if (lane == 0) {
        *(float4*)(as1 + (size_t)wid * 4) = make_float4(sv[0], sv[1], sv[2], sv[3]);
        *(float4*)(ad1 + (size_t)wid * 4) = make_float4(dv[0], dv[1], dv[2], dv[3]);
    }
}

__global__ __launch_bounds__(256) void alpha2_kernel(const float* __restrict__ g2,
                                                     const float* __restrict__ att_src,
                                                     const float* __restrict__ att_dst,
                                                     float* __restrict__ as2,
                                                     float* __restrict__ ad2, int N) {
    int wid = (blockIdx.x * 256 + threadIdx.x) >> 6;
    int lane = threadIdx.x & 63;
    if (wid >= N) return;
    float v = g2[(size_t)wid * HID + lane];
    float s = v * att_src[lane];
    float d = v * att_dst[lane];
#pragma unroll
    for (int off = 32; off; off >>= 1) {
        s += __shfl_xor(s, off, 64);
        d += __shfl_xor(d, off, 64);
    }
    if (lane == 0) { as2[wid] = s; ad2[wid] = d; }
}

// ---------------- layer-1 aggregation: one wave per dst node, online softmax over 4 heads
__global__ __launch_bounds__(256) void agg1_kernel(
    const float* __restrict__ g1, const float* __restrict__ as1, const float* __restrict__ ad1,
    const int* __restrict__ row_ptr, const int* __restrict__ colA,
    const float* __restrict__ b1, float* __restrict__ h1, int N) {
    int wid = (blockIdx.x * 256 + threadIdx.x) >> 6;
    int lane = threadIdx.x & 63;
    if (wid >= N) return;
    const float4 adv = *(const float4*)(ad1 + (size_t)wid * 4);
    float m0 = -1e30f, m1 = -1e30f, m2 = -1e30f, m3 = -1e30f;
    float s0 = 0.f, s1 = 0.f, s2 = 0.f, s3 = 0.f;
    float a0 = 0.f, a1 = 0.f, a2 = 0.f, a3 = 0.f;
    const int beg = row_ptr[wid], end = row_ptr[wid + 1];
    for (int idx = beg; idx < end; ++idx) {
        const int src = colA[idx];
        const float4 asv = *(const float4*)(as1 + (size_t)src * 4);
        const float* gr = g1 + (size_t)src * (HEADS * HID);
        const float gv0 = gr[lane];
        const float gv1 = gr[64 + lane];
        const float gv2 = gr[128 + lane];
        const float gv3 = gr[192 + lane];
        {
            float e = asv.x + adv.x; e = e > 0.f ? e : 0.2f * e;
            if (e > m0) { float sc = __expf(m0 - e); s0 = s0 * sc + 1.f; a0 = a0 * sc + gv0; m0 = e; }
            else        { float wg = __expf(e - m0); s0 += wg; a0 += wg * gv0; }
        }
        {
            float e = asv.y + adv.y; e = e > 0.f ? e : 0.2f * e;
            if (e > m1) { float sc = __expf(m1 - e); s1 = s1 * sc + 1.f; a1 = a1 * sc + gv1; m1 = e; }
            else        { float wg = __expf(e - m1); s1 += wg; a1 += wg * gv1; }
        }
        {
            float e = asv.z + adv.z; e = e > 0.f ? e : 0.2f * e;
            if (e > m2) { float sc = __expf(m2 - e); s2 = s2 * sc + 1.f; a2 = a2 * sc + gv2; m2 = e; }
            else        { float wg = __expf(e - m2); s2 += wg; a2 += wg * gv2; }
        }
        {
            float e = asv.w + adv.w; e = e > 0.f ? e : 0.2f * e;
            if (e > m3) { float sc = __expf(m3 - e); s3 = s3 * sc + 1.f; a3 = a3 * sc + gv3; m3 = e; }
            else        { float wg = __expf(e - m3); s3 += wg; a3 += wg * gv3; }
        }
    }
    float o;
    size_t base = (size_t)wid * (HEADS * HID);
    o = a0 / s0 + b1[lane];       o = o > 0.f ? o : expm1f(o); h1[base + lane] = o;
    o = a1 / s1 + b1[64 + lane];  o = o > 0.f ? o : expm1f(o); h1[base + 64 + lane] = o;
    o = a2 / s2 + b1[128 + lane]; o = o > 0.f ? o : expm1f(o); h1[base + 128 + lane] = o;
    o = a3 / s3 + b1[192 + lane]; o = o > 0.f ? o : expm1f(o); h1[base + 192 + lane] = o;
}

// ---------------- layer-2 aggregation + fused classifier ----------------
__global__ __launch_bounds__(256) void agg2_kernel(
    const float* __restrict__ g2, const float* __restrict__ as2, const float* __restrict__ ad2,
    const int* __restrict__ row_ptr, const int* __restrict__ colA,
    const float* __restrict__ b2, const float* __restrict__ Wc, const float* __restrict__ bc,
    float* __restrict__ out, int N) {
    int wid = (blockIdx.x * 256 + threadIdx.x) >> 6;
    int lane = threadIdx.x & 63;
    if (wid >= N) return;
    const float ad = ad2[wid];
    float m = -1e30f, s = 0.f, a = 0.f;
    const int beg = row_ptr[wid], end = row_ptr[wid + 1];
    for (int idx = beg; idx < end; ++idx) {
        const int src = colA[idx];
        float e = as2[src] + ad; e = e > 0.f ? e : 0.2f * e;
        const float gv = g2[(size_t)src * HID + lane];
        if (e > m) { float sc = __expf(m - e); s = s * sc + 1.f; a = a * sc + gv; m = e; }
        else       { float wg = __expf(e - m); s += wg; a += wg * gv; }
    }
    float h = a / s + b2[lane];
    h = h > 0.f ? h : expm1f(h);
    float c0 = h * Wc[lane * 2 + 0];
    float c1 = h * Wc[lane * 2 + 1];
#pragma unroll
    for (int off = 32; off; off >>= 1) {
        c0 += __shfl_xor(c0, off, 64);
        c1 += __shfl_xor(c1, off, 64);
    }
    if (lane == 0) {
        out[(size_t)wid * 2 + 0] = c0 + bc[0];
        out[(size_t)wid * 2 + 1] = c1 + bc[1];
    }
}

extern "C" void kernel_launch(void* const* d_in, const int* in_sizes, int n_in,
                              void* d_out, int out_size, void* d_ws, size_t ws_size,
                              hipStream_t stream) {
    const float* x        = (const float*)d_in[0];
    const int*   ei       = (const int*)d_in[1];   // int32 (JAX x64 disabled downcasts int64)
    const float* W1       = (const float*)d_in[2];
    const float* att1_src = (const float*)d_in[3];
    const float* att1_dst = (const float*)d_in[4];
    const float* b1       = (const float*)d_in[5];
    const float* W2       = (const float*)d_in[6];
    const float* att2_src = (const float*)d_in[7];
    const float* att2_dst = (const float*)d_in[8];
    const float* b2       = (const float*)d_in[9];
    const float* Wc       = (const float*)d_in[10];
    const float* bc       = (const float*)d_in[11];
    float* out = (float*)d_out;

    const int N = in_sizes[0] / IN_DIM;
    const int E = in_sizes[1] / 2;
    const int* srcI = ei;
    const int* dstI = ei + E;

    // workspace layout (~109 MB): g1 | h1 | as1 | ad1 | as2 | ad2 | deg | row_ptr | fill | colA
    float* ws_f = (float*)d_ws;
    float* g1  = ws_f;                        // N*256
    float* h1  = g1 + (size_t)N * 256;        // N*256
    float* as1 = h1 + (size_t)N * 256;        // N*4
    float* ad1 = as1 + (size_t)N * 4;         // N*4
    float* as2 = ad1 + (size_t)N * 4;         // N
    float* ad2 = as2 + N;                     // N
    int* deg     = (int*)(ad2 + N);           // N
    int* row_ptr = deg + N;                   // N+1
    int* fill    = row_ptr + N + 1;           // N
    int* colA    = fill + N;                  // E+N
    float* g2 = g1;                           // reuse: g1 dead after agg1

    const int nB = (N + 255) / 256;
    const int eB = (E + 255) / 256;
    const int wB = ((N * 64) + 255) / 256;    // one wave per node

    // CSR build
    deg_init_kernel<<<nB, 256, 0, stream>>>(deg, N);
    deg_count_kernel<<<eB, 256, 0, stream>>>(dstI, deg, E);
    scan_kernel<<<1, 1024, 0, stream>>>(deg, row_ptr, N);
    selfloop_kernel<<<nB, 256, 0, stream>>>(row_ptr, colA, fill, N);
    scatter_kernel<<<eB, 256, 0, stream>>>(srcI, dstI, fill, colA, E);

    // layer 1
    gemm_kernel<64><<<dim3(256 / 64, (N + 63) / 64), 256, 0, stream>>>(x, W1, g1, N, IN_DIM, 256);
    alpha1_kernel<<<wB, 256, 0, stream>>>(g1, att1_src, att1_dst, as1, ad1, N);
    agg1_kernel<<<wB, 256, 0, stream>>>(g1, as1, ad1, row_ptr, colA, b1, h1, N);

    // layer 2
    gemm_kernel<64><<<dim3(64 / 64, (N + 63) / 64), 256, 0, stream>>>(h1, W2, g2, N, 256, HID);
    alpha2_kernel<<<wB, 256, 0, stream>>>(g2, att2_src, att2_dst, as2, ad2, N);
    agg2_kernel<<<wB, 256, 0, stream>>>(g2, as2, ad2, row_ptr, colA, b2, Wc, bc, out, N);
}

// Round 3
// 409.687 us; speedup vs baseline: 1.5109x; 1.5109x over previous
//
#include <hip/hip_runtime.h>
#include <hip/hip_bf16.h>
#include <cstddef>

// ToxicityGAT: 2-layer GAT (4 heads -> 1 head) + linear classifier.
// N=50000, E=800000 (+N self loops), IN=128, HID=64, HEADS=4.
// R2 (resubmit after infra timeout): bf16 payloads (halve gather bytes),
// MFMA GEMMs, no online-max (scores bounded => exp safe, identical math
// to segment-max form), multi-block scan, depth-2 prefetch in agg loops.

#define HEADS 4
#define HID 64
#define IN_DIM 128

using bf16x8 = __attribute__((ext_vector_type(8))) short;
using f32x4  = __attribute__((ext_vector_type(4))) float;

__device__ __forceinline__ float us2f(unsigned short u) {
    return __uint_as_float((unsigned int)u << 16);
}
__device__ __forceinline__ unsigned short f2us(float f) {
    __hip_bfloat16 b = __float2bfloat16(f);
    return __builtin_bit_cast(unsigned short, b);
}

// ---------------- fp32 -> bf16 converters ----------------
__global__ __launch_bounds__(256) void cvt_x_kernel(const float* __restrict__ in,
                                                    unsigned short* __restrict__ out, int n4) {
    int i = blockIdx.x * 256 + threadIdx.x;
    if (i >= n4) return;
    float4 v = ((const float4*)in)[i];
    ushort4 o;
    o.x = f2us(v.x); o.y = f2us(v.y); o.z = f2us(v.z); o.w = f2us(v.w);
    ((ushort4*)out)[i] = o;
}

// W [K][Ncol] fp32 -> WT [Ncol][K] bf16
__global__ __launch_bounds__(256) void cvt_w_kernel(const float* __restrict__ W,
                                                    unsigned short* __restrict__ WT,
                                                    int K, int Ncol) {
    int i = blockIdx.x * 256 + threadIdx.x;
    if (i >= K * Ncol) return;
    int k = i / Ncol, n = i - k * Ncol;
    WT[(size_t)n * K + k] = f2us(W[i]);
}

// ---------------- MFMA GEMM: C[M,Nfull] = A[M,KFULL] @ BT[Nfull,KFULL]^T ----
// BM=64 fixed, 256 threads (4 waves, 16 rows each). bf16 in, fp32 acc, bf16 out.
// INTERLEAVE: layer-1 output stored head-interleaved g1b[n][d][h] (d=0..63,h=0..3)
// so agg1 reads one ushort4 per lane per edge.
template <int BN, int BK, int KFULL, bool INTERLEAVE>
__global__ __launch_bounds__(256) void gemm_mfma_kernel(
    const unsigned short* __restrict__ A,   // [M][KFULL] bf16
    const unsigned short* __restrict__ BT,  // [Nfull][KFULL] bf16
    unsigned short* __restrict__ C,         // [M][Nfull] bf16
    int M, int Nfull) {
    constexpr int LDK = BK + 8;             // pad: fragment rows spread across banks
    constexpr int NT = BN / 16;
    constexpr int KC = BK / 8;
    __shared__ unsigned short As[64 * LDK];
    __shared__ unsigned short Bs[BN * LDK];
    const int tid = threadIdx.x;
    const int wave = tid >> 6, lane = tid & 63;
    const int row0 = blockIdx.y * 64;
    const int col0 = blockIdx.x * BN;
    f32x4 acc[NT] = {};
    for (int k0 = 0; k0 < KFULL; k0 += BK) {
        for (int c = tid; c < 64 * KC; c += 256) {
            int r = c / KC, kc = c - r * KC;
            int row = row0 + r; if (row >= M) row = M - 1;  // clamp: stay in-bounds
            *(bf16x8*)(As + r * LDK + kc * 8) =
                *(const bf16x8*)(A + (size_t)row * KFULL + k0 + kc * 8);
        }
        for (int c = tid; c < BN * KC; c += 256) {
            int r = c / KC, kc = c - r * KC;
            *(bf16x8*)(Bs + r * LDK + kc * 8) =
                *(const bf16x8*)(BT + (size_t)(col0 + r) * KFULL + k0 + kc * 8);
        }
        __syncthreads();
        const int arow = wave * 16 + (lane & 15);
        const int kb = (lane >> 4) * 8;       // A/B frag: k = (l>>4)*8 + j
#pragma unroll
        for (int ks = 0; ks < BK; ks += 32) {
            bf16x8 af = *(const bf16x8*)(As + arow * LDK + ks + kb);
#pragma unroll
            for (int nt = 0; nt < NT; ++nt) {
                bf16x8 bfv = *(const bf16x8*)(Bs + (nt * 16 + (lane & 15)) * LDK + ks + kb);
                acc[nt] = __builtin_amdgcn_mfma_f32_16x16x32_bf16(af, bfv, acc[nt], 0, 0, 0);
            }
        }
        __syncthreads();
    }
    // C/D: col = lane&15, row = (lane>>4)*4 + reg  [verified mapping]
    const int crow0 = row0 + wave * 16 + ((lane >> 4) << 2);
#pragma unroll
    for (int nt = 0; nt < NT; ++nt) {
        const int col = col0 + nt * 16 + (lane & 15);
#pragma unroll
        for (int j = 0; j < 4; ++j) {
            const int row = crow0 + j;
            if (row < M) {
                size_t off = INTERLEAVE
                    ? (size_t)row * 256 + (size_t)(col & 63) * 4 + (col >> 6)
                    : (size_t)row * Nfull + col;
                C[off] = f2us(acc[nt][j]);
            }
        }
    }
}

// ---------------- CSR build ----------------
__global__ void deg_init_kernel(int* __restrict__ deg, int N) {
    int n = blockIdx.x * 256 + threadIdx.x;
    if (n < N) deg[n] = 1;  // self loop
}
__global__ void deg_count_kernel(const int* __restrict__ dst, int* __restrict__ deg, int E) {
    int e = blockIdx.x * 256 + threadIdx.x;
    if (e < E) atomicAdd(&deg[dst[e]], 1);
}
__global__ __launch_bounds__(256) void scan1_kernel(const int* __restrict__ deg,
                                                    int* __restrict__ bsum, int N) {
    const int i = blockIdx.x * 256 + threadIdx.x;
    const int lane = threadIdx.x & 63, w = threadIdx.x >> 6;
    int v = (i < N) ? deg[i] : 0;
#pragma unroll
    for (int off = 32; off; off >>= 1) v += __shfl_xor(v, off, 64);
    __shared__ int ws[4];
    if (lane == 0) ws[w] = v;
    __syncthreads();
    if (threadIdx.x == 0) bsum[blockIdx.x] = ws[0] + ws[1] + ws[2] + ws[3];
}
__global__ __launch_bounds__(256) void scan2_kernel(const int* __restrict__ bsum,
                                                    int* __restrict__ boff, int nb) {
    const int tid = threadIdx.x, lane = tid & 63, w = tid >> 6;
    int v = (tid < nb) ? bsum[tid] : 0;
    int x = v;
#pragma unroll
    for (int off = 1; off < 64; off <<= 1) {
        int y = __shfl_up(x, off, 64);
        if (lane >= off) x += y;
    }
    __shared__ int ws[4];
    if (lane == 63) ws[w] = x;
    __syncthreads();
    int add = 0;
    for (int i = 0; i < w; ++i) add += ws[i];
    x += add;
    if (tid < nb) boff[tid] = x - v;      // exclusive
    if (tid == 255) boff[nb] = x;         // total
}
__global__ __launch_bounds__(256) void scan3_kernel(const int* __restrict__ deg,
                                                    const int* __restrict__ boff,
                                                    int* __restrict__ row_ptr, int N) {
    const int i = blockIdx.x * 256 + threadIdx.x;
    const int tid = threadIdx.x, lane = tid & 63, w = tid >> 6;
    int v = (i < N) ? deg[i] : 0;
    int x = v;
#pragma unroll
    for (int off = 1; off < 64; off <<= 1) {
        int y = __shfl_up(x, off, 64);
        if (lane >= off) x += y;
    }
    __shared__ int ws[4];
    if (lane == 63) ws[w] = x;
    __syncthreads();
    int add = 0;
    for (int k = 0; k < w; ++k) add += ws[k];
    x += add;
    int excl = x - v + boff[blockIdx.x];
    if (i < N) row_ptr[i] = excl;
    if (i == N - 1) row_ptr[N] = excl + v;
}
__global__ void selfloop_kernel(const int* __restrict__ row_ptr, int* __restrict__ colA,
                                int* __restrict__ fill, int N) {
    int n = blockIdx.x * 256 + threadIdx.x;
    if (n < N) {
        int p = row_ptr[n];
        colA[p] = n;
        fill[n] = p + 1;
    }
}
__global__ void scatter_kernel(const int* __restrict__ src, const int* __restrict__ dst,
                               int* __restrict__ fill, int* __restrict__ colA, int E) {
    int e = blockIdx.x * 256 + threadIdx.x;
    if (e < E) {
        int pos = atomicAdd(&fill[dst[e]], 1);
        colA[pos] = src[e];
    }
}

// ---------------- attention score dots (one wave per node) ----------------
__global__ __launch_bounds__(256) void alpha1_kernel(const unsigned short* __restrict__ g1,
                                                     const float* __restrict__ a_src,
                                                     const float* __restrict__ a_dst,
                                                     float* __restrict__ as1,
                                                     float* __restrict__ ad1, int N) {
    int wid = (blockIdx.x * 256 + threadIdx.x) >> 6;
    int lane = threadIdx.x & 63;
    if (wid >= N) return;
    ushort4 g = *(const ushort4*)(g1 + (size_t)wid * 256 + lane * 4);  // heads 0..3 at d=lane
    float f0 = us2f(g.x), f1 = us2f(g.y), f2 = us2f(g.z), f3 = us2f(g.w);
    float s0 = f0 * a_src[lane],       d0 = f0 * a_dst[lane];
    float s1 = f1 * a_src[64 + lane],  d1 = f1 * a_dst[64 + lane];
    float s2 = f2 * a_src[128 + lane], d2 = f2 * a_dst[128 + lane];
    float s3 = f3 * a_src[192 + lane], d3 = f3 * a_dst[192 + lane];
#pragma unroll
    for (int off = 32; off; off >>= 1) {
        s0 += __shfl_xor(s0, off, 64); d0 += __shfl_xor(d0, off, 64);
        s1 += __shfl_xor(s1, off, 64); d1 += __shfl_xor(d1, off, 64);
        s2 += __shfl_xor(s2, off, 64); d2 += __shfl_xor(d2, off, 64);
        s3 += __shfl_xor(s3, off, 64); d3 += __shfl_xor(d3, off, 64);
    }
    if (lane == 0) {
        *(float4*)(as1 + (size_t)wid * 4) = make_float4(s0, s1, s2, s3);
        *(float4*)(ad1 + (size_t)wid * 4) = make_float4(d0, d1, d2, d3);
    }
}
__global__ __launch_bounds__(256) void alpha2_kernel(const unsigned short* __restrict__ g2,
                                                     const float* __restrict__ a_src,
                                                     const float* __restrict__ a_dst,
                                                     float* __restrict__ as2,
                                                     float* __restrict__ ad2, int N) {
    int wid = (blockIdx.x * 256 + threadIdx.x) >> 6;
    int lane = threadIdx.x & 63;
    if (wid >= N) return;
    float v = us2f(g2[(size_t)wid * 64 + lane]);
    float s = v * a_src[lane];
    float d = v * a_dst[lane];
#pragma unroll
    for (int off = 32; off; off >>= 1) {
        s += __shfl_xor(s, off, 64);
        d += __shfl_xor(d, off, 64);
    }
    if (lane == 0) { as2[wid] = s; ad2[wid] = d; }
}

// ---------------- layer-1 aggregation: wave per dst, plain exp (scores bounded)
__global__ __launch_bounds__(256) void agg1_kernel(
    const unsigned short* __restrict__ g1, const float* __restrict__ as1,
    const float* __restrict__ ad1, const int* __restrict__ row_ptr,
    const int* __restrict__ colA, const float* __restrict__ b1,
    unsigned short* __restrict__ h1b, int N) {
    int wid = (blockIdx.x * 256 + threadIdx.x) >> 6;
    int lane = threadIdx.x & 63;
    if (wid >= N) return;
    const float4 adv = *(const float4*)(ad1 + (size_t)wid * 4);
    float s0 = 0.f, s1 = 0.f, s2 = 0.f, s3 = 0.f;
    float a0 = 0.f, a1 = 0.f, a2 = 0.f, a3 = 0.f;
    const int beg = row_ptr[wid], end = row_ptr[wid + 1];
    int src = colA[beg];
    float4 asv = *(const float4*)(as1 + (size_t)src * 4);
    ushort4 gv = *(const ushort4*)(g1 + (size_t)src * 256 + lane * 4);
    for (int idx = beg; idx < end; ++idx) {
        const int nsrc = (idx + 1 < end) ? colA[idx + 1] : src;
        float4 nasv = *(const float4*)(as1 + (size_t)nsrc * 4);
        ushort4 ngv = *(const ushort4*)(g1 + (size_t)nsrc * 256 + lane * 4);
        float e, w;
        e = asv.x + adv.x; e = e > 0.f ? e : 0.2f * e; w = __expf(e);
        s0 += w; a0 += w * us2f(gv.x);
        e = asv.y + adv.y; e = e > 0.f ? e : 0.2f * e; w = __expf(e);
        s1 += w; a1 += w * us2f(gv.y);
        e = asv.z + adv.z; e = e > 0.f ? e : 0.2f * e; w = __expf(e);
        s2 += w; a2 += w * us2f(gv.z);
        e = asv.w + adv.w; e = e > 0.f ? e : 0.2f * e; w = __expf(e);
        s3 += w; a3 += w * us2f(gv.w);
        asv = nasv; gv = ngv;
    }
    size_t base = (size_t)wid * 256;
    float o;
    o = a0 / s0 + b1[lane];       o = o > 0.f ? o : expm1f(o); h1b[base + lane]       = f2us(o);
    o = a1 / s1 + b1[64 + lane];  o = o > 0.f ? o : expm1f(o); h1b[base + 64 + lane]  = f2us(o);
    o = a2 / s2 + b1[128 + lane]; o = o > 0.f ? o : expm1f(o); h1b[base + 128 + lane] = f2us(o);
    o = a3 / s3 + b1[192 + lane]; o = o > 0.f ? o : expm1f(o); h1b[base + 192 + lane] = f2us(o);
}

// ---------------- layer-2 aggregation + classifier ----------------
__global__ __launch_bounds__(256) void agg2_kernel(
    const unsigned short* __restrict__ g2, const float* __restrict__ as2,
    const float* __restrict__ ad2, const int* __restrict__ row_ptr,
    const int* __restrict__ colA, const float* __restrict__ b2,
    const float* __restrict__ Wc, const float* __restrict__ bc,
    float* __restrict__ out, int N) {
    int wid = (blockIdx.x * 256 + threadIdx.x) >> 6;
    int lane = threadIdx.x & 63;
    if (wid >= N) return;
    const float ad = ad2[wid];
    float s = 0.f, a = 0.f;
    const int beg = row_ptr[wid], end = row_ptr[wid + 1];
    int src = colA[beg];
    float ev = as2[src];
    unsigned short gv = g2[(size_t)src * 64 + lane];
    for (int idx = beg; idx < end; ++idx) {
        const int nsrc = (idx + 1 < end) ? colA[idx + 1] : src;
        float nev = as2[nsrc];
        unsigned short ngv = g2[(size_t)nsrc * 64 + lane];
        float e = ev + ad; e = e > 0.f ? e : 0.2f * e;
        float w = __expf(e);
        s += w; a += w * us2f(gv);
        ev = nev; gv = ngv;
    }
    float h = a / s + b2[lane];
    h = h > 0.f ? h : expm1f(h);
    float c0 = h * Wc[lane * 2 + 0];
    float c1 = h * Wc[lane * 2 + 1];
#pragma unroll
    for (int off = 32; off; off >>= 1) {
        c0 += __shfl_xor(c0, off, 64);
        c1 += __shfl_xor(c1, off, 64);
    }
    if (lane == 0) {
        out[(size_t)wid * 2 + 0] = c0 + bc[0];
        out[(size_t)wid * 2 + 1] = c1 + bc[1];
    }
}

extern "C" void kernel_launch(void* const* d_in, const int* in_sizes, int n_in,
                              void* d_out, int out_size, void* d_ws, size_t ws_size,
                              hipStream_t stream) {
    const float* x        = (const float*)d_in[0];
    const int*   ei       = (const int*)d_in[1];
    const float* W1       = (const float*)d_in[2];
    const float* att1_src = (const float*)d_in[3];
    const float* att1_dst = (const float*)d_in[4];
    const float* b1       = (const float*)d_in[5];
    const float* W2       = (const float*)d_in[6];
    const float* att2_src = (const float*)d_in[7];
    const float* att2_dst = (const float*)d_in[8];
    const float* b2       = (const float*)d_in[9];
    const float* Wc       = (const float*)d_in[10];
    const float* bc       = (const float*)d_in[11];
    float* out = (float*)d_out;

    const int N = in_sizes[0] / IN_DIM;
    const int E = in_sizes[1] / 2;
    const int* srcI = ei;
    const int* dstI = ei + E;

    // workspace layout (bf16 buffers first, then fp32, then ints) ~76 MB
    unsigned short* g1b = (unsigned short*)d_ws;      // N*256 (head-interleaved)
    unsigned short* h1b = g1b + (size_t)N * 256;      // N*256
    unsigned short* xb  = h1b + (size_t)N * 256;      // N*128
    unsigned short* g2b = xb + (size_t)N * 128;       // N*64
    unsigned short* W1T = g2b + (size_t)N * 64;       // 256*128
    unsigned short* W2T = W1T + 256 * 128;            // 64*256
    float* as1 = (float*)(W2T + 64 * 256);            // N*4
    float* ad1 = as1 + (size_t)N * 4;                 // N*4
    float* as2 = ad1 + (size_t)N * 4;                 // N
    float* ad2 = as2 + N;                             // N
    int* deg     = (int*)(ad2 + N);                   // N
    int* row_ptr = deg + N;                           // N+1
    int* fill    = row_ptr + N + 1;                   // N
    int* bsum    = fill + N;                          // 256
    int* boff    = bsum + 256;                        // 257
    int* colA    = boff + 260;                        // E+N

    const int nB = (N + 255) / 256;
    const int eB = (E + 255) / 256;
    const int wB = ((N * 64) + 255) / 256;            // one wave per node
    const int nb = nB;                                // scan partials (<=256)

    // converters (independent of CSR)
    cvt_x_kernel<<<(N * (IN_DIM / 4) + 255) / 256, 256, 0, stream>>>(x, xb, N * (IN_DIM / 4));
    cvt_w_kernel<<<(IN_DIM * 256 + 255) / 256, 256, 0, stream>>>(W1, W1T, IN_DIM, 256);
    cvt_w_kernel<<<(256 * 64 + 255) / 256, 256, 0, stream>>>(W2, W2T, 256, 64);

    // CSR build
    deg_init_kernel<<<nB, 256, 0, stream>>>(deg, N);
    deg_count_kernel<<<eB, 256, 0, stream>>>(dstI, deg, E);
    scan1_kernel<<<nB, 256, 0, stream>>>(deg, bsum, N);
    scan2_kernel<<<1, 256, 0, stream>>>(bsum, boff, nb);
    scan3_kernel<<<nB, 256, 0, stream>>>(deg, boff, row_ptr, N);
    selfloop_kernel<<<nB, 256, 0, stream>>>(row_ptr, colA, fill, N);
    scatter_kernel<<<eB, 256, 0, stream>>>(srcI, dstI, fill, colA, E);

    // layer 1: g1 = x @ W1 (bf16 MFMA), head-interleaved output
    gemm_mfma_kernel<128, 128, 128, true>
        <<<dim3(2, (N + 63) / 64), 256, 0, stream>>>(xb, W1T, g1b, N, 256);
    alpha1_kernel<<<wB, 256, 0, stream>>>(g1b, att1_src, att1_dst, as1, ad1, N);
    agg1_kernel<<<wB, 256, 0, stream>>>(g1b, as1, ad1, row_ptr, colA, b1, h1b, N);

    // layer 2: g2 = h1 @ W2 (bf16 MFMA)
    gemm_mfma_kernel<64, 128, 256, false>
        <<<dim3(1, (N + 63) / 64), 256, 0, stream>>>(h1b, W2T, g2b, N, 64);
    alpha2_kernel<<<wB, 256, 0, stream>>>(g2b, att2_src, att2_dst, as2, ad2, N);
    agg2_kernel<<<wB, 256, 0, stream>>>(g2b, as2, ad2, row_ptr, colA, b2, Wc, bc, out, N);
}